// Round 3
// baseline (524.072 us; speedup 1.0000x reference)
//
#include <hip/hip_runtime.h>
#include <math.h>

// Problem constants (from setup_inputs): B=16384 rows, C=4096 cols, NBINS=1000.
constexpr int BROWS = 16384;
constexpr int CCOLS = 4096;
constexpr int BLOCK = 512;                // 8 waves/block
constexpr int WAVES = 8;
constexpr int GRID  = 512;                // 2 blocks/CU on 256 CUs, all resident
constexpr int RPB   = BROWS / GRID;       // 32 rows per block
constexpr int V4PT  = CCOLS / BLOCK / 4;  // 2 float4 per thread per array
constexpr int EPT   = 4 * V4PT;           // 8 elements per thread per row
constexpr int CHUNKS_PW = CCOLS * 4 / 1024 / WAVES;  // 2 x 1KB DMA chunks/wave/array

// base-2 formulation: v_exp_f32/v_log_f32 are natively base-2 on gfx9.
constexpr float INV_LN2      = 1.4426950408889634f;
constexpr float LN2          = 0.6931471805599453f;
constexpr float LOG2_EPS     = -23.253496664211536f;  // log2(1e-7)
constexpr float LOG2_1M_EPS  = -1.4426951e-7f;        // log2(1 - 1e-7)

__device__ __forceinline__ float fast_exp2(float x) {
#if __has_builtin(__builtin_amdgcn_exp2f)
    return __builtin_amdgcn_exp2f(x);
#else
    return __expf(x * LN2);
#endif
}
__device__ __forceinline__ float fast_log2(float x) {
#if __has_builtin(__builtin_amdgcn_logf)
    return __builtin_amdgcn_logf(x);   // log base 2
#else
    return __log2f(x);
#endif
}

__device__ __forceinline__ float wave_reduce_sum(float v) {
#pragma unroll
    for (int m = 32; m > 0; m >>= 1) v += __shfl_xor(v, m, 64);
    return v;
}
__device__ __forceinline__ float wave_reduce_max(float v) {
#pragma unroll
    for (int m = 32; m > 0; m >>= 1) v = fmaxf(v, __shfl_xor(v, m, 64));
    return v;
}
__device__ __forceinline__ double wave_reduce_sum_d(double v) {
#pragma unroll
    for (int m = 32; m > 0; m >>= 1) v += __shfl_xor(v, m, 64);
    return v;
}

// async 16B-per-lane global->LDS DMA. LDS dest is wave-uniform base + lane*16;
// global src is per-lane. Linear-linear mapping (no swizzle) -> LDS[i] = row[i].
__device__ __forceinline__ void async_cp16(const float* g, float* l) {
    __builtin_amdgcn_global_load_lds(
        (__attribute__((address_space(1))) void*)(const_cast<float*>(g)),
        (__attribute__((address_space(3))) void*)(l), 16, 0, 0);
}

// Stage one row-pair into LDS buffers: 16KB yp + 16KB yt, 4 DMA instrs per wave.
__device__ __forceinline__ void stage_row(const float* yp_row, const float* yt_row,
                                          float* s_yp, float* s_yt,
                                          int wave, int lane) {
    const int lelem = lane * 4;               // this lane's 16B within a 1KB chunk
#pragma unroll
    for (int j = 0; j < CHUNKS_PW; ++j) {
        const int coff = (wave * CHUNKS_PW + j) * 256;   // chunk offset in floats
        async_cp16(yp_row + coff + lelem, s_yp + coff);
        async_cp16(yt_row + coff + lelem, s_yt + coff);
    }
}

// -(bce term) in base-2 units: y*log2(clip p) + (1-y)*log2(clip(1-p)).
__device__ __forceinline__ float nbce2(float x2, float y, float off2) {
    float z2 = x2 - off2;                                   // log2 softmax
    float zc = fminf(fmaxf(z2, LOG2_EPS), LOG2_1M_EPS);     // log2(clip(p))
    float p  = fast_exp2(z2);
    float l2 = fast_log2(1.0f - p);                         // log2(1-p)
    l2 = fminf(fmaxf(l2, LOG2_EPS), LOG2_1M_EPS);           // log2(clip(1-p))
    return fmaf(y, zc - l2, l2);                            // y*zc + (1-y)*l2
}

__global__ void __launch_bounds__(BLOCK, 4)   // LDS-bound at 2 blocks/CU anyway
wce_main_kernel(const float* __restrict__ y_pred,
                const float* __restrict__ y_true,
                const float* __restrict__ weights,
                const int*   __restrict__ cond,
                float* __restrict__ partials)
{
    __shared__ float  s_yp[2][CCOLS];   // 32 KB double-buffered y_pred row
    __shared__ float  s_yt[2][CCOLS];   // 32 KB double-buffered y_true row
    __shared__ float2 s_ms[WAVES];      // per-wave (max2, sum) publish
    __shared__ float  s_nb[WAVES];      // per-wave bce publish
    __shared__ float  s_w[RPB];         // per-row weights, gathered once

    const int tid  = threadIdx.x;
    const int wave = tid >> 6;
    const int lane = tid & 63;
    const int row0 = blockIdx.x * RPB;

    // once-per-block: gather the 32 row weights (off the per-row critical path)
    if (tid < RPB) s_w[tid] = weights[cond[row0 + tid]];

    // prologue: DMA row 0 into buffer 0
    stage_row(y_pred + (size_t)row0 * CCOLS, y_true + (size_t)row0 * CCOLS,
              s_yp[0], s_yt[0], wave, lane);

#pragma unroll 2
    for (int r = 0; r < RPB; ++r) {
        const int cur = r & 1;
        const int nxt = cur ^ 1;

        // ---- issue next-row DMA, then wait for CURRENT row only (counted vmcnt:
        //      4 newest stay in flight across the barrier) ----
        if (r + 1 < RPB) {
            const size_t b = (size_t)(row0 + r + 1) * CCOLS;
            stage_row(y_pred + b, y_true + b, s_yp[nxt], s_yt[nxt], wave, lane);
            asm volatile("s_waitcnt vmcnt(4)" ::: "memory");
        } else {
            asm volatile("s_waitcnt vmcnt(0)" ::: "memory");
        }
        __builtin_amdgcn_s_barrier();             // (A) row r staged, all waves
        __builtin_amdgcn_sched_barrier(0);

        // ---- pass 1: read yp from LDS, base-2 convert, wave max ----
        const float4* yp4 = (const float4*)s_yp[cur];
        float x2[EPT];
        float m2w = -3.4e38f;
#pragma unroll
        for (int i = 0; i < V4PT; ++i) {
            const float4 a = yp4[tid + BLOCK * i];
            x2[4*i+0] = a.x * INV_LN2;
            x2[4*i+1] = a.y * INV_LN2;
            x2[4*i+2] = a.z * INV_LN2;
            x2[4*i+3] = a.w * INV_LN2;
            m2w = fmaxf(m2w, fmaxf(fmaxf(x2[4*i+0], x2[4*i+1]),
                                   fmaxf(x2[4*i+2], x2[4*i+3])));
        }
        m2w = wave_reduce_max(m2w);

        // ---- pass 2: wave-local sum of 2^(x2 - m2w) ----
        float s2w = 0.0f;
#pragma unroll
        for (int i = 0; i < EPT; ++i) s2w += fast_exp2(x2[i] - m2w);
        s2w = wave_reduce_sum(s2w);
        if (lane == 0) s_ms[wave] = make_float2(m2w, s2w);
        asm volatile("s_waitcnt lgkmcnt(0)" ::: "memory");
        __builtin_amdgcn_s_barrier();             // (B) (max,sum) visible

        // ---- combine per-wave pairs (redundantly in all threads) ----
        float2 msl[WAVES];
        float  m2 = -3.4e38f;
#pragma unroll
        for (int i = 0; i < WAVES; ++i) { msl[i] = s_ms[i]; m2 = fmaxf(m2, msl[i].x); }
        float s = 0.0f;
#pragma unroll
        for (int i = 0; i < WAVES; ++i) s += msl[i].y * fast_exp2(msl[i].x - m2);
        const float off2 = m2 + fast_log2(s);     // log2-softmax offset

        // ---- pass 3: read yt from LDS, clipped BCE ----
        const float4* yt4 = (const float4*)s_yt[cur];
        float nb = 0.0f;
#pragma unroll
        for (int i = 0; i < V4PT; ++i) {
            const float4 tt = yt4[tid + BLOCK * i];
            nb += nbce2(x2[4*i+0], tt.x, off2);
            nb += nbce2(x2[4*i+1], tt.y, off2);
            nb += nbce2(x2[4*i+2], tt.z, off2);
            nb += nbce2(x2[4*i+3], tt.w, off2);
        }
        nb = wave_reduce_sum(nb);
        if (lane == 0) s_nb[wave] = nb;
        asm volatile("s_waitcnt lgkmcnt(0)" ::: "memory");
        __builtin_amdgcn_s_barrier();             // (C) bce visible; buf reuse safe

        if (tid == 0) {
            float rnb = s_nb[0];
#pragma unroll
            for (int i = 1; i < WAVES; ++i) rnb += s_nb[i];
            partials[row0 + r] = -s_w[r] * LN2 * rnb;   // back to nat-log units
        }
    }
}

// Reduce BROWS partials (f32) in double, divide, write the scalar loss.
__global__ void __launch_bounds__(256)
wce_reduce_kernel(const float* __restrict__ partials, float* __restrict__ out)
{
    __shared__ double s_part[4];
    const int tid  = threadIdx.x;
    const int wave = tid >> 6;
    const int lane = tid & 63;

    const float4* p4 = (const float4*)partials;
    double s = 0.0;
#pragma unroll
    for (int i = 0; i < BROWS / (256 * 4); ++i) {   // 16 iters
        float4 p = p4[tid + 256 * i];
        s += (double)p.x + (double)p.y + (double)p.z + (double)p.w;
    }
    s = wave_reduce_sum_d(s);
    if (lane == 0) s_part[wave] = s;
    __syncthreads();
    if (tid == 0) {
        double total = (s_part[0] + s_part[1]) + (s_part[2] + s_part[3]);
        out[0] = (float)(total / ((double)BROWS * (double)CCOLS));
    }
}

extern "C" void kernel_launch(void* const* d_in, const int* in_sizes, int n_in,
                              void* d_out, int out_size, void* d_ws, size_t ws_size,
                              hipStream_t stream) {
    const float* y_pred  = (const float*)d_in[0];
    const float* y_true  = (const float*)d_in[1];
    const float* weights = (const float*)d_in[2];
    const int*   cond    = (const int*)d_in[3];
    float* out      = (float*)d_out;
    float* partials = (float*)d_ws;   // BROWS floats = 64 KB scratch

    wce_main_kernel<<<GRID, BLOCK, 0, stream>>>(y_pred, y_true, weights, cond, partials);
    wce_reduce_kernel<<<1, 256, 0, stream>>>(partials, out);
}